// Round 2
// baseline (436.316 us; speedup 1.0000x reference)
//
#include <hip/hip_runtime.h>
#include <cstdint>
#include <cstddef>

#define THREADS 256
#define FTHREADS 512

typedef __attribute__((ext_vector_type(8))) short short8;   // 8 bf16 = 4 VGPR (MFMA A/B frag)
typedef __attribute__((ext_vector_type(4))) float f32x4;    // MFMA C/D frag

#define MFMA(a, b, c) __builtin_amdgcn_mfma_f32_16x16x32_bf16((a), (b), (c), 0, 0, 0)

static constexpr int kC    = 128;
static constexpr int kImgC = 128 * 256;   // 32768 coarse px / image
static constexpr int kImgF = 256 * 512;   // 131072 fine px / image

// fp32 -> bf16 RNE (integer math; inputs are never NaN here)
__device__ __forceinline__ unsigned short f2bf(float f) {
  unsigned u = __builtin_bit_cast(unsigned, f);
  u += 0x7fffu + ((u >> 16) & 1u);
  return (unsigned short)(u >> 16);
}
// pack two floats -> bf16x2 as uint (lo in low half)
__device__ __forceinline__ unsigned pack_bf16(float lo, float hi) {
  return (unsigned)f2bf(lo) | ((unsigned)f2bf(hi) << 16);
}
__device__ __forceinline__ float bf_up(unsigned short u) {
  return __builtin_bit_cast(float, (unsigned)u << 16);
}

// A-frag: lane l supplies A[m=px][k=c]: px = mt*16+(l&15), c = kt*32+(l>>4)*8+j
// element (px,c) at byte: px*256 + (((c>>3) ^ (px&7))*16) + (c&7)*2
__device__ __forceinline__ short8 ldA(const char* lds, int mt, int kt, int l) {
  const int px = mt * 16 + (l & 15);
  const int chunk = (kt * 4 + (l >> 4)) ^ (px & 7);
  return *(const short8*)(lds + px * 256 + chunk * 16);
}

// ---------- kernel 0: cast all weights fp32 [o][c] -> bf16 [o][c] ----------
// wbuf layout (shorts): Wq@0(8192) Wk@8192(8192) Wvp@16384(16384) Wvi@32768(16384) Wout@49152(16384)
__global__ __launch_bounds__(THREADS) void cast_w(
    const float* __restrict__ Wq, const float* __restrict__ Wk,
    const float* __restrict__ Wvp, const float* __restrict__ Wvi,
    const float* __restrict__ Wout, unsigned short* __restrict__ dst) {
  int i = blockIdx.x * THREADS + threadIdx.x;   // 0..65535
  float v;
  if (i < 8192)       v = Wq[i];
  else if (i < 16384) v = Wk[i - 8192];
  else if (i < 32768) v = Wvp[i - 16384];
  else if (i < 49152) v = Wvi[i - 32768];
  else                v = Wout[i - 49152];
  dst[i] = f2bf(v);
}

// ---------- fused kernel: k/v production + q + attention + v_init + out ----------
// One block = 2 fine rows x 64 cols (one coarse row y2). The 3x34 coarse k/v
// window is COMPUTED in-block: stage h_prev window as bf16 A-tile -> MFMA with
// Wk/Wvp -> ks_/vs_ in LDS (OOB cells zero-masked AFTER the GEMM so unfold's
// zero-pad semantics hold exactly: score 0 participates in softmax, v adds 0).
__global__ __launch_bounds__(FTHREADS, 2) void fine_fused(
    const float* __restrict__ h_prev, const float* __restrict__ h_init,
    const unsigned short* __restrict__ wbuf,
    const float* __restrict__ bq, const float* __restrict__ bk,
    const float* __restrict__ bvp, const float* __restrict__ bvi,
    const float* __restrict__ bout, float* __restrict__ out) {
  __shared__ char xs[32768];                 // h_prev win tile, then x/t-tile (bf16 swz)
  __shared__ unsigned short qs[128 * 72];    // q  [px][72]  (stride 144 B)
  __shared__ float ks_[102 * 76];            // k  [cell][76]  f32 (stride 304 B)
  __shared__ float vs_[102 * 140];           // v  [cell][140] f32 (stride 560 B)

  const int tid = threadIdx.x;
  const int l = tid & 63, w = tid >> 6;      // 8 waves
  const int m = l & 15, g = l >> 4;

  const int bid = blockIdx.x;                // 0..2047
  const int b   = bid >> 10;                 // image
  const int r10 = bid & 1023;
  const int y2  = r10 >> 3;                  // coarse row 0..127
  const int x0  = (r10 & 7) * 64;            // fine col base
  const int x20 = x0 >> 1;                   // coarse col base

  const size_t fbase = (size_t)b * kC * kImgF;

  const short8* wqp = (const short8*)wbuf;
  const short8* wkp = (const short8*)(wbuf + 8192);
  const short8* wvp = (const short8*)(wbuf + 16384);
  const short8* wip = (const short8*)(wbuf + 32768);
  const short8* wop = (const short8*)(wbuf + 49152);

  // ---- phase A: issue h_init loads into registers (HBM latency hides under B+C)
  const int tl = tid & 255;
  const int sl = tl & 63, sw = tl >> 6;
  const int spxl = sl & 7, scg = sl >> 3;
  const float* xsrc = h_init + fbase + (size_t)(2 * y2 + (tid >> 8)) * 512 + x0;
  float xf0[16], xf1[16];
  #pragma unroll
  for (int i = 0; i < 16; ++i) {
    const int px = spxl + 8 * (i & 7);
    const int c  = 2 * (scg + 8 * (sw + 4 * (i >> 3)));
    xf0[i] = xsrc[(size_t)c * kImgF + px];
    xf1[i] = xsrc[(size_t)(c + 1) * kImgF + px];
  }

  // ---- phase B: stage h_prev 3x34-cell window as bf16 A-tile in xs ----
  // cell index p = cy*34+cx (0..101); wave w owns channel-pair group w.
  {
    const float* hp = h_prev + (size_t)b * kC * kImgC;
    const int pxl = l & 7, cg8 = l >> 3;
    const int c = 2 * (cg8 + 8 * w);         // even channel 0..126
    #pragma unroll
    for (int t = 0; t < 13; ++t) {
      const int p = pxl + 8 * t;             // cell 0..103
      const int cy = p / 34, cx = p - cy * 34;
      const int yy = y2 + cy - 1, xx = x20 + cx - 1;
      float f0 = 0.f, f1 = 0.f;
      if (p < 102 && (unsigned)yy < 128u && (unsigned)xx < 256u) {
        const size_t pos = (size_t)yy * 256 + xx;
        f0 = hp[(size_t)c * kImgC + pos];
        f1 = hp[(size_t)(c + 1) * kImgC + pos];
      }
      if (p < 102) {
        const int chunk = (c >> 3) ^ (p & 7);
        *(unsigned*)(xs + p * 256 + chunk * 16 + (c & 7) * 2) = pack_bf16(f0, f1);
      }
    }
  }
  __syncthreads();

  // ---- phase C: kv-GEMM -> ks_/vs_ (f32), OOB cells forced to 0 ----
  // 84 jobs = 7 m-tiles x (4 k-grp + 8 v-grp); round-robin over 8 waves.
  for (int j = w; j < 84; j += 8) {
    const int mt = j / 12, cg12 = j - mt * 12;
    const bool isk = cg12 < 4;
    const int och = (isk ? cg12 : cg12 - 4) * 16 + m;
    const short8* wp = isk ? wkp : wvp;
    const float bl = isk ? bk[och] : bvp[och];
    f32x4 acc = {bl, bl, bl, bl};
    #pragma unroll
    for (int kt = 0; kt < 4; ++kt)
      acc = MFMA(ldA(xs, mt, kt, l), wp[och * 16 + kt * 4 + g], acc);
    #pragma unroll
    for (int r = 0; r < 4; ++r) {
      const int cell = mt * 16 + g * 4 + r;
      if (cell < 102) {
        const int cy = cell / 34, cx = cell - cy * 34;
        const int yy = y2 + cy - 1, xx = x20 + cx - 1;
        const float val =
            ((unsigned)yy < 128u && (unsigned)xx < 256u) ? acc[r] : 0.f;
        if (isk) ks_[cell * 76 + och] = val;
        else     vs_[cell * 140 + och] = val;
      }
    }
  }
  __syncthreads();

  // ---- phase D: sink h_init registers into xs (overwrite h_prev tile) ----
  {
    char* dst = xs + (tid >> 8) * 16384;
    #pragma unroll
    for (int i = 0; i < 16; ++i) {
      const int px = spxl + 8 * (i & 7);
      const int c  = 2 * (scg + 8 * (sw + 4 * (i >> 3)));
      const int chunk = (c >> 3) ^ (px & 7);
      *(unsigned*)(dst + px * 256 + chunk * 16 + (c & 7) * 2) =
          pack_bf16(xf0[i], xf1[i]);
    }
  }
  __syncthreads();

  // ---- GEMM1: q = x * Wq^T -> qs (bf16). wave: px-half (w>>2), ch-grp ((w&3)*16)
  const int chq4 = (w & 3) * 16 + m;
  const int hh   = w >> 2;
  {
    short8 fq[4];
    #pragma unroll
    for (int kt = 0; kt < 4; ++kt) fq[kt] = wqp[chq4 * 16 + kt * 4 + g];
    const float bl = bq[chq4];
    #pragma unroll
    for (int mt = 0; mt < 4; ++mt) {
      f32x4 acc = {bl, bl, bl, bl};
      #pragma unroll
      for (int kt = 0; kt < 4; ++kt) acc = MFMA(ldA(xs, hh * 4 + mt, kt, l), fq[kt], acc);
      #pragma unroll
      for (int r = 0; r < 4; ++r)
        qs[(hh * 64 + mt * 16 + g * 4 + r) * 72 + chq4] = f2bf(acc[r]);
    }
  }

  // ---- GEMM2: v_init = x * Wvi^T -> registers (wave owns ch-group w*16, all 128 px)
  const int ch = w * 16 + m;
  f32x4 vacc[8];
  {
    short8 fi[4];
    #pragma unroll
    for (int kt = 0; kt < 4; ++kt) fi[kt] = wip[ch * 16 + kt * 4 + g];
    const float bl = bvi[ch];
    #pragma unroll
    for (int mt = 0; mt < 8; ++mt) {
      f32x4 acc = {bl, bl, bl, bl};
      #pragma unroll
      for (int kt = 0; kt < 4; ++kt) acc = MFMA(ldA(xs, mt, kt, l), fi[kt], acc);
      vacc[mt] = acc;
    }
  }
  __syncthreads();   // all xs reads done

  // ---- write v_init into xs as swizzled bf16 t-tile init ----
  #pragma unroll
  for (int mt = 0; mt < 8; ++mt) {
    #pragma unroll
    for (int r = 0; r < 4; ++r) {
      const int px = mt * 16 + g * 4 + r;
      const int chunk = (ch >> 3) ^ (px & 7);
      *(unsigned short*)(xs + px * 256 + chunk * 16 + (ch & 7) * 2) = f2bf(vacc[mt][r]);
    }
  }
  __syncthreads();   // t-init + qs ready

  // ---- attention: 4 threads per fine px; all reads from LDS ----
  {
    const int apx = tid >> 2;                // 0..127
    const int sub = tid & 3;
    const int cc  = ((apx & 63) >> 1) + 1;   // center col in window

    float qf[16];
    {
      const uint4* qp = (const uint4*)((const char*)qs + apx * 144 + sub * 32);
      const uint4 u0 = qp[0], u1 = qp[1];
      const unsigned uu[8] = {u0.x, u0.y, u0.z, u0.w, u1.x, u1.y, u1.z, u1.w};
      #pragma unroll
      for (int i = 0; i < 8; ++i) {
        qf[2 * i]     = __builtin_bit_cast(float, uu[i] << 16);
        qf[2 * i + 1] = __builtin_bit_cast(float, uu[i] & 0xffff0000u);
      }
    }

    float a[9];
    #pragma unroll
    for (int j = 0; j < 9; ++j) {
      const int cell = (j / 3) * 34 + cc + (j % 3) - 1;
      const float4* kp = (const float4*)(ks_ + cell * 76 + sub * 16);
      const float4 k0 = kp[0], k1 = kp[1], k2 = kp[2], k3 = kp[3];
      float s = qf[0]*k0.x + qf[1]*k0.y + qf[2]*k0.z + qf[3]*k0.w
              + qf[4]*k1.x + qf[5]*k1.y + qf[6]*k1.z + qf[7]*k1.w
              + qf[8]*k2.x + qf[9]*k2.y + qf[10]*k2.z + qf[11]*k2.w
              + qf[12]*k3.x + qf[13]*k3.y + qf[14]*k3.z + qf[15]*k3.w;
      s += __shfl_xor(s, 1);
      s += __shfl_xor(s, 2);
      a[j] = s;
    }
    float mx = a[0];
    #pragma unroll
    for (int j = 1; j < 9; ++j) mx = fmaxf(mx, a[j]);
    float den = 0.f;
    #pragma unroll
    for (int j = 0; j < 9; ++j) { a[j] = __expf(a[j] - mx); den += a[j]; }
    const float inv = 1.f / den;

    float tt[32];
    #pragma unroll
    for (int i = 0; i < 32; ++i) tt[i] = 0.f;
    #pragma unroll
    for (int j = 0; j < 9; ++j) {
      const int cell = (j / 3) * 34 + cc + (j % 3) - 1;
      const float aj = a[j] * inv;
      const float4* vp = (const float4*)(vs_ + cell * 140 + sub * 32);
      const float4 v0 = vp[0], v1 = vp[1], v2 = vp[2], v3 = vp[3];
      const float4 v4 = vp[4], v5 = vp[5], v6 = vp[6], v7 = vp[7];
      tt[0]+=aj*v0.x;  tt[1]+=aj*v0.y;  tt[2]+=aj*v0.z;  tt[3]+=aj*v0.w;
      tt[4]+=aj*v1.x;  tt[5]+=aj*v1.y;  tt[6]+=aj*v1.z;  tt[7]+=aj*v1.w;
      tt[8]+=aj*v2.x;  tt[9]+=aj*v2.y;  tt[10]+=aj*v2.z; tt[11]+=aj*v2.w;
      tt[12]+=aj*v3.x; tt[13]+=aj*v3.y; tt[14]+=aj*v3.z; tt[15]+=aj*v3.w;
      tt[16]+=aj*v4.x; tt[17]+=aj*v4.y; tt[18]+=aj*v4.z; tt[19]+=aj*v4.w;
      tt[20]+=aj*v5.x; tt[21]+=aj*v5.y; tt[22]+=aj*v5.z; tt[23]+=aj*v5.w;
      tt[24]+=aj*v6.x; tt[25]+=aj*v6.y; tt[26]+=aj*v6.z; tt[27]+=aj*v6.w;
      tt[28]+=aj*v7.x; tt[29]+=aj*v7.y; tt[30]+=aj*v7.z; tt[31]+=aj*v7.w;
    }
    // t = v_init + attn  (RMW this thread's exclusive (px, 32ch) slice of xs)
    #pragma unroll
    for (int i = 0; i < 16; ++i) {
      const int c2 = sub * 32 + 2 * i;
      const int chunk = (c2 >> 3) ^ (apx & 7);
      unsigned* p = (unsigned*)(xs + apx * 256 + chunk * 16 + (c2 & 7) * 2);
      const unsigned u = *p;
      const float lo = bf_up((unsigned short)u) + tt[2 * i];
      const float hi = bf_up((unsigned short)(u >> 16)) + tt[2 * i + 1];
      *p = pack_bf16(lo, hi);
    }
  }
  __syncthreads();

  // ---- GEMM3: out = t * Wout^T (wave owns ch-group w*16, all 128 px) ----
  {
    short8 fo[4];
    #pragma unroll
    for (int kt = 0; kt < 4; ++kt) fo[kt] = wop[ch * 16 + kt * 4 + g];
    const float bl = bout[ch];
    #pragma unroll
    for (int mt = 0; mt < 8; ++mt) {
      f32x4 acc = {bl, bl, bl, bl};
      #pragma unroll
      for (int kt = 0; kt < 4; ++kt) acc = MFMA(ldA(xs, mt, kt, l), fo[kt], acc);
      const int px = mt * 16 + g * 4;
      *(float4*)(out + fbase + (size_t)ch * kImgF
                 + (size_t)(2 * y2 + (px >> 6)) * 512 + x0 + (px & 63)) =
          make_float4(acc[0], acc[1], acc[2], acc[3]);
    }
  }
}

// ---------- launch ----------
extern "C" void kernel_launch(void* const* d_in, const int* in_sizes, int n_in,
                              void* d_out, int out_size, void* d_ws, size_t ws_size,
                              hipStream_t stream) {
  const float* h_prev = (const float*)d_in[0];
  const float* h_init = (const float*)d_in[1];
  const float* Wq   = (const float*)d_in[2];
  const float* bq   = (const float*)d_in[3];
  const float* Wk   = (const float*)d_in[4];
  const float* bk   = (const float*)d_in[5];
  const float* Wvp  = (const float*)d_in[6];
  const float* bvp  = (const float*)d_in[7];
  const float* Wvi  = (const float*)d_in[8];
  const float* bvi  = (const float*)d_in[9];
  const float* Wout = (const float*)d_in[10];
  const float* bout = (const float*)d_in[11];
  float* out = (float*)d_out;

  char* ws = (char*)d_ws;
  unsigned short* wbuf = (unsigned short*)ws;                  // 65536 shorts = 131072 B

  cast_w<<<256, THREADS, 0, stream>>>(Wq, Wk, Wvp, Wvi, Wout, wbuf);
  fine_fused<<<2048, FTHREADS, 0, stream>>>(h_prev, h_init, wbuf,
                                            bq, bk, bvp, bvi, bout, out);
}

// Round 3
// 369.027 us; speedup vs baseline: 1.1823x; 1.1823x over previous
//
#include <hip/hip_runtime.h>
#include <cstdint>
#include <cstddef>

#define THREADS 256
#define FTHREADS 512

typedef __attribute__((ext_vector_type(8))) short short8;   // 8 bf16 = 4 VGPR (MFMA A/B frag)
typedef __attribute__((ext_vector_type(4))) float f32x4;    // MFMA C/D frag

#define MFMA(a, b, c) __builtin_amdgcn_mfma_f32_16x16x32_bf16((a), (b), (c), 0, 0, 0)

static constexpr int kC    = 128;
static constexpr int kImgC = 128 * 256;   // 32768 coarse px / image
static constexpr int kImgF = 256 * 512;   // 131072 fine px / image

// fp32 -> bf16 RNE (integer math; inputs are never NaN here)
__device__ __forceinline__ unsigned short f2bf(float f) {
  unsigned u = __builtin_bit_cast(unsigned, f);
  u += 0x7fffu + ((u >> 16) & 1u);
  return (unsigned short)(u >> 16);
}
// pack two floats -> bf16x2 as uint (lo in low half)
__device__ __forceinline__ unsigned pack_bf16(float lo, float hi) {
  return (unsigned)f2bf(lo) | ((unsigned)f2bf(hi) << 16);
}
__device__ __forceinline__ float bf_up(unsigned short u) {
  return __builtin_bit_cast(float, (unsigned)u << 16);
}
__device__ __forceinline__ float bf_lo(unsigned u) {
  return __builtin_bit_cast(float, u << 16);
}
__device__ __forceinline__ float bf_hi(unsigned u) {
  return __builtin_bit_cast(float, u & 0xffff0000u);
}

// A-frag: lane l supplies A[m=px][k=c]: px = mt*16+(l&15), c = kt*32+(l>>4)*8+j
// element (px,c) at byte: px*256 + (((c>>3) ^ (px&7))*16) + (c&7)*2
__device__ __forceinline__ short8 ldA(const char* lds, int mt, int kt, int l) {
  const int px = mt * 16 + (l & 15);
  const int chunk = (kt * 4 + (l >> 4)) ^ (px & 7);
  return *(const short8*)(lds + px * 256 + chunk * 16);
}

// ---------- kernel 0: cast all weights fp32 [o][c] -> bf16 [o][c] ----------
// wbuf layout (shorts): Wq@0(8192) Wk@8192(8192) Wvp@16384(16384) Wvi@32768(16384) Wout@49152(16384)
__global__ __launch_bounds__(THREADS) void cast_w(
    const float* __restrict__ Wq, const float* __restrict__ Wk,
    const float* __restrict__ Wvp, const float* __restrict__ Wvi,
    const float* __restrict__ Wout, unsigned short* __restrict__ dst) {
  int i = blockIdx.x * THREADS + threadIdx.x;   // 0..65535
  float v;
  if (i < 8192)       v = Wq[i];
  else if (i < 16384) v = Wk[i - 8192];
  else if (i < 32768) v = Wvp[i - 16384];
  else if (i < 49152) v = Wvi[i - 32768];
  else                v = Wout[i - 49152];
  dst[i] = f2bf(v);
}

// ---------- kernel 1: coarse k,v via MFMA -> bf16 kbuf/vbuf ----------
// kbuf: [px][64] bf16, vbuf: [px][128] bf16 (px = global coarse pixel)
__global__ __launch_bounds__(THREADS, 4) void coarse_kv(
    const float* __restrict__ h_prev, const unsigned short* __restrict__ wbuf,
    const float* __restrict__ bk, const float* __restrict__ bvp,
    unsigned short* __restrict__ kbuf, unsigned short* __restrict__ vbuf) {
  __shared__ char xs[16384];
  const int tid = threadIdx.x;
  const int l = tid & 63, w = tid >> 6;
  const int m = l & 15, g = l >> 4;
  const int chq = w * 16 + m;

  const int tile = blockIdx.x;              // 0..1023
  const int b    = tile >> 9;
  const int p0   = (tile & 511) * 64;       // within-image coarse px base
  const int p0g  = tile * 64;               // global coarse px base

  const short8* wkp = (const short8*)(wbuf + 8192);
  const short8* wvp = (const short8*)(wbuf + 16384);
  short8 fk[4], fv[2][4];
  #pragma unroll
  for (int kt = 0; kt < 4; ++kt) fk[kt] = wkp[chq * 16 + kt * 4 + g];
  #pragma unroll
  for (int nt = 0; nt < 2; ++nt)
    #pragma unroll
    for (int kt = 0; kt < 4; ++kt)
      fv[nt][kt] = wvp[(nt * 64 + chq) * 16 + kt * 4 + g];

  // stage 64px x 128ch fp32 -> swizzled bf16 A-tile
  {
    const float* src = h_prev + (size_t)b * kC * kImgC + p0;
    const int pxl = l & 7, cg = l >> 3;
    #pragma unroll
    for (int i = 0; i < 16; ++i) {
      const int px = pxl + 8 * (i & 7);
      const int c  = 2 * (cg + 8 * (w + 4 * (i >> 3)));
      float f0 = src[(size_t)c * kImgC + px];
      float f1 = src[(size_t)(c + 1) * kImgC + px];
      const int chunk = (c >> 3) ^ (px & 7);
      *(unsigned*)(xs + px * 256 + chunk * 16 + (c & 7) * 2) = pack_bf16(f0, f1);
    }
  }
  __syncthreads();

  {  // k: 64 out channels
    const float bl = bk[chq];
    #pragma unroll
    for (int mt = 0; mt < 4; ++mt) {
      f32x4 acc = {bl, bl, bl, bl};
      #pragma unroll
      for (int kt = 0; kt < 4; ++kt) acc = MFMA(ldA(xs, mt, kt, l), fk[kt], acc);
      #pragma unroll
      for (int r = 0; r < 4; ++r)
        kbuf[(size_t)(p0g + mt * 16 + g * 4 + r) * 64 + chq] = f2bf(acc[r]);
    }
  }
  #pragma unroll
  for (int nt = 0; nt < 2; ++nt) {  // v: 128 out channels
    const float bl = bvp[nt * 64 + chq];
    #pragma unroll
    for (int mt = 0; mt < 4; ++mt) {
      f32x4 acc = {bl, bl, bl, bl};
      #pragma unroll
      for (int kt = 0; kt < 4; ++kt) acc = MFMA(ldA(xs, mt, kt, l), fv[nt][kt], acc);
      #pragma unroll
      for (int r = 0; r < 4; ++r)
        vbuf[(size_t)(p0g + mt * 16 + g * 4 + r) * 128 + nt * 64 + chq] = f2bf(acc[r]);
    }
  }
}

// ---------- kernel 2: fused fine pass, 8 fine rows x 16 cols per block ----------
// Window = 6x10 = 60 coarse cells (squarer tile -> 41% less halo than 3x34).
// k/v staged as bf16 with bank-uniform padding; LDS total 78 KB -> 2 blocks/CU
// so one block's compute hides the other's staging latency.
__global__ __launch_bounds__(FTHREADS, 4) void fine_fused(
    const float* __restrict__ h_init, const unsigned short* __restrict__ wbuf,
    const float* __restrict__ bq, const float* __restrict__ bvi,
    const float* __restrict__ bout,
    const unsigned short* __restrict__ kbuf, const unsigned short* __restrict__ vbuf,
    float* __restrict__ out) {
  __shared__ char xs[32768];                 // x-tile (bf16 swz), later t-tile; px 0..127
  __shared__ unsigned short qs[128 * 72];    // q  [px][72]        (stride 144 B)
  __shared__ unsigned short ks_[60 * 80];    // k  [cell][4][20]   (sub-stride 40 B)
  __shared__ unsigned short vs_[60 * 144];   // v  [cell][4][36]   (sub-stride 72 B)

  const int tid = threadIdx.x;
  const int l = tid & 63, w = tid >> 6;      // 8 waves
  const int m = l & 15, g = l >> 4;

  const int bid = blockIdx.x;                // 0..2047
  const int b   = bid >> 10;                 // image
  const int r10 = bid & 1023;
  const int ty  = r10 >> 5;                  // tile row 0..31
  const int tx  = r10 & 31;                  // tile col 0..31
  const int y0  = ty * 8;                    // fine row base
  const int x0  = tx * 16;                   // fine col base
  const int y20 = y0 >> 1;                   // coarse row base (4 rows)
  const int x20 = x0 >> 1;                   // coarse col base (8 cols)

  const size_t fbase = (size_t)b * kC * kImgF;
  const unsigned short* kb = kbuf + (size_t)b * kImgC * 64;
  const unsigned short* vb = vbuf + (size_t)b * kImgC * 128;

  const short8* wqp = (const short8*)wbuf;
  const short8* wip = (const short8*)(wbuf + 32768);
  const short8* wop = (const short8*)(wbuf + 49152);

  // ---- stage x-tile: 512 threads, 128 px x 128 ch ----
  {
    const int half = tid >> 8;               // px 0..63 / 64..127
    const int tl = tid & 255;
    const int sl = tl & 63, sw = tl >> 6;
    const int pxl = sl & 7, cg = sl >> 3;
    #pragma unroll
    for (int i = 0; i < 16; ++i) {
      const int px = half * 64 + pxl + 8 * (i & 7);
      const int row = px >> 4, col = px & 15;
      const int c  = 2 * (cg + 8 * (sw + 4 * (i >> 3)));
      const size_t off = (size_t)(y0 + row) * 512 + x0 + col;
      float f0 = h_init[fbase + (size_t)c * kImgF + off];
      float f1 = h_init[fbase + (size_t)(c + 1) * kImgF + off];
      const int chunk = (c >> 3) ^ (px & 7);
      *(unsigned*)(xs + px * 256 + chunk * 16 + (c & 7) * 2) = pack_bf16(f0, f1);
    }
  }

  // ---- stage k window: 60 cells x 16 chunks of 4ch (uint2), zero-fill OOB ----
  #pragma unroll
  for (int it = 0; it < 2; ++it) {
    const int i = tid + it * 512;
    if (i < 960) {
      const int cell = i >> 4, cp = i & 15;
      const int cy = cell / 10, cx = cell - cy * 10;
      const int yy = y20 + cy - 1, xx = x20 + cx - 1;
      uint2 val = make_uint2(0u, 0u);
      if ((unsigned)yy < 128u && (unsigned)xx < 256u)
        val = *(const uint2*)(kb + ((size_t)yy * 256 + xx) * 64 + cp * 4);
      *(uint2*)((char*)ks_ + cell * 160 + (cp >> 2) * 40 + (cp & 3) * 8) = val;
    }
  }
  // ---- stage v window: 60 cells x 32 chunks of 4ch (uint2), zero-fill OOB ----
  #pragma unroll
  for (int it = 0; it < 4; ++it) {
    const int i = tid + it * 512;
    if (i < 1920) {
      const int cell = i >> 5, cp = i & 31;
      const int cy = cell / 10, cx = cell - cy * 10;
      const int yy = y20 + cy - 1, xx = x20 + cx - 1;
      uint2 val = make_uint2(0u, 0u);
      if ((unsigned)yy < 128u && (unsigned)xx < 256u)
        val = *(const uint2*)(vb + ((size_t)yy * 256 + xx) * 128 + cp * 4);
      *(uint2*)((char*)vs_ + cell * 288 + (cp >> 3) * 72 + (cp & 7) * 8) = val;
    }
  }
  __syncthreads();

  // ---- GEMM1: q = x * Wq^T -> qs (bf16). wave: px-half (w>>2), ch-grp ((w&3)*16)
  const int chq4 = (w & 3) * 16 + m;
  const int hh   = w >> 2;
  {
    short8 fq[4];
    #pragma unroll
    for (int kt = 0; kt < 4; ++kt) fq[kt] = wqp[chq4 * 16 + kt * 4 + g];
    const float bl = bq[chq4];
    #pragma unroll
    for (int mt = 0; mt < 4; ++mt) {
      f32x4 acc = {bl, bl, bl, bl};
      #pragma unroll
      for (int kt = 0; kt < 4; ++kt) acc = MFMA(ldA(xs, hh * 4 + mt, kt, l), fq[kt], acc);
      #pragma unroll
      for (int r = 0; r < 4; ++r)
        qs[(hh * 64 + mt * 16 + g * 4 + r) * 72 + chq4] = f2bf(acc[r]);
    }
  }

  // ---- GEMM2: v_init = x * Wvi^T -> registers (wave owns ch-group w*16, all 128 px)
  const int ch = w * 16 + m;
  f32x4 vacc[8];
  {
    short8 fi[4];
    #pragma unroll
    for (int kt = 0; kt < 4; ++kt) fi[kt] = wip[ch * 16 + kt * 4 + g];
    const float bl = bvi[ch];
    #pragma unroll
    for (int mt = 0; mt < 8; ++mt) {
      f32x4 acc = {bl, bl, bl, bl};
      #pragma unroll
      for (int kt = 0; kt < 4; ++kt) acc = MFMA(ldA(xs, mt, kt, l), fi[kt], acc);
      vacc[mt] = acc;
    }
  }
  __syncthreads();   // all xs reads done

  // ---- write v_init into xs as swizzled bf16 t-tile init ----
  #pragma unroll
  for (int mt = 0; mt < 8; ++mt) {
    #pragma unroll
    for (int r = 0; r < 4; ++r) {
      const int px = mt * 16 + g * 4 + r;
      const int chunk = (ch >> 3) ^ (px & 7);
      *(unsigned short*)(xs + px * 256 + chunk * 16 + (ch & 7) * 2) = f2bf(vacc[mt][r]);
    }
  }
  __syncthreads();   // t-init + qs ready

  // ---- attention: 4 threads per fine px; all reads from LDS (bf16) ----
  {
    const int apx = tid >> 2;                // 0..127
    const int sub = tid & 3;
    const int r2  = apx >> 5;                // (row>>1): window row base
    const int c2  = (apx & 15) >> 1;         // window col base

    float qf[16];
    {
      const uint4* qp = (const uint4*)((const char*)qs + apx * 144 + sub * 32);
      const uint4 u0 = qp[0], u1 = qp[1];
      const unsigned uu[8] = {u0.x, u0.y, u0.z, u0.w, u1.x, u1.y, u1.z, u1.w};
      #pragma unroll
      for (int i = 0; i < 8; ++i) {
        qf[2 * i]     = bf_lo(uu[i]);
        qf[2 * i + 1] = bf_hi(uu[i]);
      }
    }

    float a[9];
    #pragma unroll
    for (int j = 0; j < 9; ++j) {
      const int cell = (r2 + j / 3) * 10 + c2 + (j % 3);
      const char* kc = (const char*)ks_ + cell * 160 + sub * 40;
      const uint2 u0 = *(const uint2*)kc;
      const uint2 u1 = *(const uint2*)(kc + 8);
      const uint2 u2 = *(const uint2*)(kc + 16);
      const uint2 u3 = *(const uint2*)(kc + 24);
      const unsigned uu[8] = {u0.x, u0.y, u1.x, u1.y, u2.x, u2.y, u3.x, u3.y};
      float s = 0.f;
      #pragma unroll
      for (int i = 0; i < 8; ++i)
        s += qf[2 * i] * bf_lo(uu[i]) + qf[2 * i + 1] * bf_hi(uu[i]);
      s += __shfl_xor(s, 1);
      s += __shfl_xor(s, 2);
      a[j] = s;
    }
    float mx = a[0];
    #pragma unroll
    for (int j = 1; j < 9; ++j) mx = fmaxf(mx, a[j]);
    float den = 0.f;
    #pragma unroll
    for (int j = 0; j < 9; ++j) { a[j] = __expf(a[j] - mx); den += a[j]; }
    const float inv = 1.f / den;

    float tt[32];
    #pragma unroll
    for (int i = 0; i < 32; ++i) tt[i] = 0.f;
    #pragma unroll
    for (int j = 0; j < 9; ++j) {
      const int cell = (r2 + j / 3) * 10 + c2 + (j % 3);
      const float aj = a[j] * inv;
      const char* vc = (const char*)vs_ + cell * 288 + sub * 72;
      #pragma unroll
      for (int q2 = 0; q2 < 8; ++q2) {
        const uint2 u = *(const uint2*)(vc + q2 * 8);
        tt[4 * q2]     += aj * bf_lo(u.x);
        tt[4 * q2 + 1] += aj * bf_hi(u.x);
        tt[4 * q2 + 2] += aj * bf_lo(u.y);
        tt[4 * q2 + 3] += aj * bf_hi(u.y);
      }
    }
    // t = v_init + attn  (RMW this thread's exclusive (px, 32ch) slice of xs)
    #pragma unroll
    for (int i = 0; i < 16; ++i) {
      const int cc2 = sub * 32 + 2 * i;
      const int chunk = (cc2 >> 3) ^ (apx & 7);
      unsigned* p = (unsigned*)(xs + apx * 256 + chunk * 16 + (cc2 & 7) * 2);
      const unsigned u = *p;
      const float lo = bf_lo(u) + tt[2 * i];
      const float hi = bf_up((unsigned short)(u >> 16)) + tt[2 * i + 1];
      *p = pack_bf16(lo, hi);
    }
  }
  __syncthreads();

  // ---- GEMM3: out = t * Wout^T (wave owns ch-group w*16, all 128 px) ----
  {
    short8 fo[4];
    #pragma unroll
    for (int kt = 0; kt < 4; ++kt) fo[kt] = wop[ch * 16 + kt * 4 + g];
    const float bl = bout[ch];
    #pragma unroll
    for (int mt = 0; mt < 8; ++mt) {
      f32x4 acc = {bl, bl, bl, bl};
      #pragma unroll
      for (int kt = 0; kt < 4; ++kt) acc = MFMA(ldA(xs, mt, kt, l), fo[kt], acc);
      // px = mt*16 + g*4 + r -> row = mt, cols g*4..g*4+3 (contiguous)
      *(float4*)(out + fbase + (size_t)ch * kImgF
                 + (size_t)(y0 + mt) * 512 + x0 + g * 4) =
          make_float4(acc[0], acc[1], acc[2], acc[3]);
    }
  }
}

// ---------- launch ----------
extern "C" void kernel_launch(void* const* d_in, const int* in_sizes, int n_in,
                              void* d_out, int out_size, void* d_ws, size_t ws_size,
                              hipStream_t stream) {
  const float* h_prev = (const float*)d_in[0];
  const float* h_init = (const float*)d_in[1];
  const float* Wq   = (const float*)d_in[2];
  const float* bq   = (const float*)d_in[3];
  const float* Wk   = (const float*)d_in[4];
  const float* bk   = (const float*)d_in[5];
  const float* Wvp  = (const float*)d_in[6];
  const float* bvp  = (const float*)d_in[7];
  const float* Wvi  = (const float*)d_in[8];
  const float* bvi  = (const float*)d_in[9];
  const float* Wout = (const float*)d_in[10];
  const float* bout = (const float*)d_in[11];
  float* out = (float*)d_out;

  char* ws = (char*)d_ws;
  unsigned short* wbuf = (unsigned short*)ws;                    // 131072 B
  unsigned short* kbuf = (unsigned short*)(ws + 131072);         // 65536*64*2 = 8 MB
  unsigned short* vbuf = (unsigned short*)(ws + 131072 + (size_t)65536 * 64 * 2); // 16 MB

  cast_w<<<256, THREADS, 0, stream>>>(Wq, Wk, Wvp, Wvi, Wout, wbuf);
  coarse_kv<<<1024, THREADS, 0, stream>>>(h_prev, wbuf, bk, bvp, kbuf, vbuf);
  fine_fused<<<2048, FTHREADS, 0, stream>>>(h_init, wbuf, bq, bvi, bout,
                                            kbuf, vbuf, out);
}